// Round 19
// baseline (91.750 us; speedup 1.0000x reference)
//
#include <hip/hip_runtime.h>
#include <hip/hip_bf16.h>

#define BB 4
#define TT 4096
#define DM 1024
#define DK 64
#define NSPLIT 8

using f32x4  = __attribute__((ext_vector_type(4))) float;
using bf16x8 = __attribute__((ext_vector_type(8))) short;

__device__ __forceinline__ short f2bf(float f) {
    __hip_bfloat16 h = __float2bfloat16(f);
    return __builtin_bit_cast(short, h);
}
__device__ __forceinline__ float bf2f(short s) {
    unsigned int u = ((unsigned int)(unsigned short)s) << 16;
    return __builtin_bit_cast(float, u);
}

// ---------------- Kernel 0: pack Wq|Wk|Wv (f32 [1024][64]) -> Wt bf16 [192][1024]
__global__ __launch_bounds__(256) void wt_kernel(const float* __restrict__ Wq,
                                                 const float* __restrict__ Wk,
                                                 const float* __restrict__ Wv,
                                                 short* __restrict__ Wt) {
    int idx = blockIdx.x * 256 + threadIdx.x;
    if (idx >= 192 * 1024) return;
    int n = idx >> 10;
    int m = idx & 1023;
    const float* W = (n < 64) ? Wq : (n < 128) ? Wk : Wv;
    int c = n & 63;
    Wt[idx] = f2bf(W[m * 64 + c]);
}

// ---------------- Kernel 1: FUSED QKV projection, B direct-from-L2 (no B staging)
// A (x tile, 32x64 f32) staged in LDS dbuf (16 KB total); B fragments loaded
// straight from Wt (L2-hot, 384 KB) into a double-set register pipeline
// (bA/bB, one chunk lookahead). 24 MFMA/chunk/wave. Grid 512 = 2 blocks/CU.
// q is pre-scaled by 1/8 (folded attention scale).
__global__ __launch_bounds__(256, 2) void proj_rope(const float* __restrict__ x,
                                                    const float* __restrict__ freqs,
                                                    const short* __restrict__ Wt,
                                                    short* __restrict__ q,
                                                    short* __restrict__ k,
                                                    short* __restrict__ vt)
{
    __shared__ float As[2][2048];     // [32 rows][16 units of f32x4], XOR-swizzled; 8 KB each

    int t  = threadIdx.x;
    int w  = t >> 6;
    int l  = t & 63;
    int lr = l & 15;
    int lg = (l >> 4) & 3;
    int wr = w & 1;                   // row group (16 rows)
    int wc = w >> 1;                  // col group (32 cols)
    int bx = blockIdx.x;
    int mt = (bx & 7) * 64 + (bx >> 3);   // 0..511, XCD-striped
    int m0 = mt * 32;

    // A staging geometry: 32 rows x 16 units, 2 units/thread
    int arow = t >> 3;                // 0..31
    int au   = (t & 7) * 2;           // first of 2 f32x4 units
    int aswz = arow & 7;
    const float* gA = x + (size_t)(m0 + arow) * DM + au * 4;

    // B base pointers: 6 lane-rows of Wt (nh x ntl), column lg*8
    const short* gb[6];
#pragma unroll
    for (int nh = 0; nh < 3; ++nh)
#pragma unroll
        for (int ntl = 0; ntl < 2; ++ntl)
            gb[nh * 2 + ntl] = Wt + (size_t)(nh * 64 + (wc * 2 + ntl) * 16 + lr) * DM + lg * 8;

    f32x4 ar[2];
    bf16x8 bA[12], bB[12];

#define LOADA(c_) do { int kk = (c_) << 6;                      \
        ar[0] = *(const f32x4*)(gA + kk);                       \
        ar[1] = *(const f32x4*)(gA + kk + 4);                   \
    } while (0)

#define WRITEA(buf_) do {                                                      \
        *(f32x4*)&As[buf_][arow * 64 + (((au    ) ^ aswz) << 2)] = ar[0];      \
        *(f32x4*)&As[buf_][arow * 64 + (((au + 1) ^ aswz) << 2)] = ar[1];      \
    } while (0)

#define LOADB(dst_, c_) do { int kk = (c_) << 6;                               \
        _Pragma("unroll")                                                      \
        for (int j_ = 0; j_ < 6; ++j_) {                                       \
            dst_[j_]     = *(const bf16x8*)(gb[j_] + kk);                      \
            dst_[6 + j_] = *(const bf16x8*)(gb[j_] + kk + 32);                 \
        }                                                                      \
    } while (0)

    f32x4 acc[6];                     // [nh*2+ntl]
#pragma unroll
    for (int i = 0; i < 6; ++i) acc[i] = (f32x4){0.f, 0.f, 0.f, 0.f};

    int r7 = lr & 7;
    int amrow = (wr * 16 + lr) * 64;
    int cur = 0;

#define COMPUTE(BS) do {                                                       \
        _Pragma("unroll")                                                      \
        for (int s_ = 0; s_ < 2; ++s_) {                                       \
            int u0_ = s_ * 8 + lg * 2;                                         \
            f32x4 a0_ = *(const f32x4*)&As[cur][amrow + (((u0_    ) ^ r7) << 2)]; \
            f32x4 a1_ = *(const f32x4*)&As[cur][amrow + (((u0_ + 1) ^ r7) << 2)]; \
            bf16x8 af_;                                                        \
            _Pragma("unroll")                                                  \
            for (int j_ = 0; j_ < 4; ++j_) { af_[j_] = f2bf(a0_[j_]); af_[4 + j_] = f2bf(a1_[j_]); } \
            _Pragma("unroll")                                                  \
            for (int j_ = 0; j_ < 6; ++j_)                                     \
                acc[j_] = __builtin_amdgcn_mfma_f32_16x16x32_bf16(af_, BS[s_ * 6 + j_], acc[j_], 0, 0, 0); \
        }                                                                      \
    } while (0)

    // prologue
    LOADA(0); WRITEA(0);
    LOADB(bA, 0);
    LOADA(1);
    __syncthreads();

#pragma unroll
    for (int ch = 0; ch < 16; ch += 2) {
        // even chunk (ch): compute with bA, prefetch bB for ch+1
        LOADB(bB, ch + 1);
        COMPUTE(bA);
        WRITEA(cur ^ 1);                       // chunk ch+1's A (loaded earlier)
        if (ch + 2 < 16) LOADA(ch + 2);
        __syncthreads();
        cur ^= 1;

        // odd chunk (ch+1): compute with bB, prefetch bA for ch+2
        if (ch + 2 < 16) LOADB(bA, ch + 2);
        COMPUTE(bB);
        if (ch + 2 < 16) {                     // A-dance only if a next chunk exists
            WRITEA(cur ^ 1);                   // chunk ch+2's A
            if (ch + 3 < 16) LOADA(ch + 3);
            __syncthreads();
            cur ^= 1;
        }
    }
#undef LOADA
#undef WRITEA
#undef LOADB
#undef COMPUTE

    // ---- q, k epilogue with fused RoPE
#pragma unroll
    for (int nh = 0; nh < 2; ++nh) {
        short* dst = nh ? k : q;
        float postscale = nh ? 1.0f : 0.125f;
#pragma unroll
        for (int r = 0; r < 4; ++r) {
            int tg = m0 + wr * 16 + lg * 4 + r;
            int tt = tg & (TT - 1);
#pragma unroll
            for (int ntl = 0; ntl < 2; ++ntl) {
                int c = wc * 32 + ntl * 16 + lr;
                float e = acc[nh * 2 + ntl][r];
                float p = __shfl_xor(e, 1);
                float2 f = ((const float2*)freqs)[(size_t)tt * 32 + (c >> 1)];
                float sgn = (c & 1) ? f.y : -f.y;
                dst[(size_t)tg * DK + c] = f2bf((e * f.x + p * sgn) * postscale);
            }
        }
    }

    // ---- V epilogue: stage 32x64 bf16 in LDS (reuse As), write vt[b][c][t] coalesced
    __syncthreads();
    short* vs = (short*)&As[0][0];
#pragma unroll
    for (int r = 0; r < 4; ++r)
#pragma unroll
        for (int ntl = 0; ntl < 2; ++ntl)
            vs[(wr * 16 + lg * 4 + r) * 64 + wc * 32 + ntl * 16 + lr] = f2bf(acc[4 + ntl][r]);
    __syncthreads();
    int b    = mt >> 7;
    int tt0  = (mt & 127) * 32;
    int c    = t >> 2;
    int tgrp = t & 3;
    bf16x8 v0;
#pragma unroll
    for (int j = 0; j < 8; ++j) v0[j] = vs[(tgrp * 8 + j) * 64 + c];
    *(bf16x8*)(vt + ((size_t)b * DK + c) * TT + tt0 + tgrp * 8) = v0;
}

// ---------------- Kernel 2: causal flash attention (R8 config — best measured, (256,4))
__global__ __launch_bounds__(256, 4) void attn_kernel(const short* __restrict__ q,
                                                      const short* __restrict__ k,
                                                      const short* __restrict__ vt,
                                                      short* __restrict__ po,
                                                      float* __restrict__ ml)
{
    __shared__ short Kb[64][64];
    __shared__ short Vb[64][64];
    __shared__ short pbuf[4][16][72];

    int w  = threadIdx.x >> 6;
    int l  = threadIdx.x & 63;
    int lr = l & 15;
    int lg = l >> 4;
    int b  = blockIdx.y;
    int s  = blockIdx.z;
    int qt = 63 - blockIdx.x;
    int q0 = qt * 64;
    int qrow_wave = q0 + w * 16;

    const short* qB = q  + (size_t)b * TT * DK;
    const short* kB = k  + (size_t)b * TT * DK;
    const short* vB = vt + (size_t)b * DK * TT;

    bf16x8 qf0 = *(const bf16x8*)(qB + (size_t)(qrow_wave + lr) * DK + 8 * lg);
    bf16x8 qf1 = *(const bf16x8*)(qB + (size_t)(qrow_wave + lr) * DK + 32 + 8 * lg);

    f32x4 of[4];
#pragma unroll
    for (int i = 0; i < 4; ++i) of[i] = (f32x4){0.f, 0.f, 0.f, 0.f};
    float m[4], lsum[4];
#pragma unroll
    for (int r = 0; r < 4; ++r) { m[r] = -INFINITY; lsum[r] = 0.f; }

    int nt = (qt >= s) ? ((qt - s + NSPLIT) >> 3) : 0;

    int srow = threadIdx.x >> 2;
    int u0   = (threadIdx.x & 3) * 2;
    int p0s  = ((u0) ^ (srow & 7)) * 8;
    int p1s  = ((u0 + 1) ^ (srow & 7)) * 8;

    bf16x8 kr0, kr1, vr0, vr1;
    short* mypb = &pbuf[w][0][0];

#define ISSUE(tile_) do {                                                        \
        int kv0_ = (tile_) << 6;                                                 \
        const short* gk_ = kB + (size_t)(kv0_ + srow) * DK + (u0 * 8);           \
        const short* gv_ = vB + (size_t)srow * TT + kv0_ + (u0 * 8);             \
        kr0 = *(const bf16x8*)gk_; kr1 = *(const bf16x8*)(gk_ + 8);              \
        vr0 = *(const bf16x8*)gv_; vr1 = *(const bf16x8*)(gv_ + 8);              \
    } while (0)

#define WRITE() do {                                                             \
        *(bf16x8*)&Kb[srow][p0s] = kr0;                                         \
        *(bf16x8*)&Kb[srow][p1s] = kr1;                                         \
        *(bf16x8*)&Vb[srow][p0s] = vr0;                                         \
        *(bf16x8*)&Vb[srow][p1s] = vr1;                                         \
    } while (0)

    if (nt > 0) {
        ISSUE(s); WRITE();
        if (nt > 1) ISSUE(s + NSPLIT);
        __syncthreads();
        for (int i = 0; i < nt; ++i) {
            int kv0 = (s + i * NSPLIT) << 6;

            // ---- QK^T
            f32x4 sc[4];
#pragma unroll
            for (int c = 0; c < 4; ++c) sc[c] = (f32x4){0.f, 0.f, 0.f, 0.f};
#pragma unroll
            for (int c = 0; c < 4; ++c) {
                int row = c * 16 + lr;
                bf16x8 kf0 = *(const bf16x8*)&Kb[row][((lg) ^ (row & 7)) * 8];
                bf16x8 kf1 = *(const bf16x8*)&Kb[row][((4 + lg) ^ (row & 7)) * 8];
                sc[c] = __builtin_amdgcn_mfma_f32_16x16x32_bf16(qf0, kf0, sc[c], 0, 0, 0);
                sc[c] = __builtin_amdgcn_mfma_f32_16x16x32_bf16(qf1, kf1, sc[c], 0, 0, 0);
            }

            // ---- mask only on the diagonal tile
            if (kv0 == q0) {
#pragma unroll
                for (int r = 0; r < 4; ++r) {
                    int qg = qrow_wave + lg * 4 + r;
#pragma unroll
                    for (int c = 0; c < 4; ++c)
                        sc[c][r] = (kv0 + c * 16 + lr <= qg) ? sc[c][r] : -INFINITY;
                }
            }

            // ---- local per-lane row max; gate the expensive path on it
            float mx[4];
#pragma unroll
            for (int r = 0; r < 4; ++r)
                mx[r] = fmaxf(fmaxf(sc[0][r], sc[1][r]), fmaxf(sc[2][r], sc[3][r]));
            bool needA = (mx[0] > m[0] + 8.f) || (mx[1] > m[1] + 8.f) ||
                         (mx[2] > m[2] + 8.f) || (mx[3] > m[3] + 8.f);
            if (__any(needA)) {
#pragma unroll
                for (int r = 0; r < 4; ++r) {
                    float t2 = mx[r];
                    t2 = fmaxf(t2, __shfl_xor(t2, 1));
                    t2 = fmaxf(t2, __shfl_xor(t2, 2));
                    t2 = fmaxf(t2, __shfl_xor(t2, 4));
                    t2 = fmaxf(t2, __shfl_xor(t2, 8));
                    float mn = fmaxf(m[r], t2);
                    float alpha = __expf(m[r] - mn);   // uniform across 16-lane group
                    m[r] = mn;
                    lsum[r] *= alpha;                  // per-lane partial scaled exactly
#pragma unroll
                    for (int dt = 0; dt < 4; ++dt) of[dt][r] *= alpha;
                }
            }
#pragma unroll
            for (int r = 0; r < 4; ++r) {
                float p0 = __expf(sc[0][r] - m[r]);
                float p1 = __expf(sc[1][r] - m[r]);
                float p2 = __expf(sc[2][r] - m[r]);
                float p3 = __expf(sc[3][r] - m[r]);
                lsum[r] += (p0 + p1) + (p2 + p3);      // reduce deferred to epilogue
                int prow = (lg * 4 + r) * 72;
                mypb[prow + lr]      = f2bf(p0);
                mypb[prow + 16 + lr] = f2bf(p1);
                mypb[prow + 32 + lr] = f2bf(p2);
                mypb[prow + 48 + lr] = f2bf(p3);
            }

            // ---- PV
#pragma unroll
            for (int ks = 0; ks < 2; ++ks) {
                bf16x8 pa = *(const bf16x8*)(mypb + lr * 72 + ks * 32 + 8 * lg);
#pragma unroll
                for (int dt = 0; dt < 4; ++dt) {
                    int row = dt * 16 + lr;
                    bf16x8 vf = *(const bf16x8*)&Vb[row][((ks * 4 + lg) ^ (row & 7)) * 8];
                    of[dt] = __builtin_amdgcn_mfma_f32_16x16x32_bf16(pa, vf, of[dt], 0, 0, 0);
                }
            }

            if (i + 1 < nt) {
                __syncthreads();                 // all waves done reading Kb/Vb
                WRITE();                          // next tile regs -> LDS
                if (i + 2 < nt) ISSUE(s + (i + 2) * NSPLIT);
                __syncthreads();                 // writes visible
            }
        }
    }
#undef ISSUE
#undef WRITE

    // epilogue: one cross-lane lsum reduce
#pragma unroll
    for (int r = 0; r < 4; ++r) {
        float ps = lsum[r];
        ps += __shfl_xor(ps, 1);
        ps += __shfl_xor(ps, 2);
        ps += __shfl_xor(ps, 4);
        ps += __shfl_xor(ps, 8);
        lsum[r] = ps;
    }

    short* myo  = po + (((size_t)b * 64 + qt) * NSPLIT + s) * 4096;
    float* myml = ml + (((size_t)b * 64 + qt) * NSPLIT + s) * 128;
#pragma unroll
    for (int r = 0; r < 4; ++r) {
        int row = w * 16 + lg * 4 + r;
#pragma unroll
        for (int dt = 0; dt < 4; ++dt) myo[row * 64 + dt * 16 + lr] = f2bf(of[dt][r]);
        if (lr == 0) { myml[row] = m[r]; myml[64 + row] = lsum[r]; }
    }
}

// ---------------- Kernel 3: merge the 8 kv-split partials (po bf16)
__global__ __launch_bounds__(256) void merge_kernel(const short* __restrict__ po,
                                                    const float* __restrict__ ml,
                                                    float* __restrict__ out)
{
    int qt = blockIdx.x;
    int b  = blockIdx.y;
    int row = threadIdx.x >> 2;
    int cg  = threadIdx.x & 3;

    size_t mlbase = ((size_t)b * 64 + qt) * NSPLIT * 128;
    float mm[NSPLIT], llv[NSPLIT];
#pragma unroll
    for (int s = 0; s < NSPLIT; ++s) {
        mm[s]  = ml[mlbase + s * 128 + row];
        llv[s] = ml[mlbase + s * 128 + 64 + row];
    }
    float M = -INFINITY;
#pragma unroll
    for (int s = 0; s < NSPLIT; ++s) M = fmaxf(M, mm[s]);
    float e[NSPLIT], den = 0.f;
#pragma unroll
    for (int s = 0; s < NSPLIT; ++s) { e[s] = __expf(mm[s] - M); den += e[s] * llv[s]; }
    float inv = 1.0f / den;

    size_t pbase = ((size_t)b * 64 + qt) * NSPLIT * 4096;
#pragma unroll
    for (int jj = 0; jj < 2; ++jj) {
        int col = cg * 16 + jj * 8;
        float acc8[8];
#pragma unroll
        for (int e2 = 0; e2 < 8; ++e2) acc8[e2] = 0.f;
#pragma unroll
        for (int s = 0; s < NSPLIT; ++s) {
            bf16x8 v = *(const bf16x8*)(po + pbase + s * 4096 + row * 64 + col);
#pragma unroll
            for (int e2 = 0; e2 < 8; ++e2) acc8[e2] += e[s] * bf2f(v[e2]);
        }
        float* orow = out + ((size_t)b * TT + qt * 64 + row) * DK + col;
#pragma unroll
        for (int e2 = 0; e2 < 8; ++e2) orow[e2] = acc8[e2] * inv;
    }
}

extern "C" void kernel_launch(void* const* d_in, const int* in_sizes, int n_in,
                              void* d_out, int out_size, void* d_ws, size_t ws_size,
                              hipStream_t stream) {
    const float* x     = (const float*)d_in[0];
    const float* freqs = (const float*)d_in[1];
    const float* Wq    = (const float*)d_in[2];
    const float* Wk    = (const float*)d_in[3];
    const float* Wv    = (const float*)d_in[4];
    float* out = (float*)d_out;

    char* ws = (char*)d_ws;
    short* Wt  = (short*)ws;                          // 384 KB
    short* qb  = (short*)(ws + 393216);               // 2 MB
    short* kb  = (short*)(ws + 2490368);              // 2 MB
    short* vtb = (short*)(ws + 4587520);              // 2 MB
    short* po  = (short*)(ws + 6684672);              // 16 MB partial O (bf16)
    float* ml  = (float*)(ws + 23461888);             // 1 MB partial m/l

    hipLaunchKernelGGL(wt_kernel, dim3(768), dim3(256), 0, stream, Wq, Wk, Wv, Wt);
    hipLaunchKernelGGL(proj_rope, dim3(512), dim3(256), 0, stream, x, freqs, Wt, qb, kb, vtb);
    hipLaunchKernelGGL(attn_kernel, dim3(64, BB, NSPLIT), dim3(256), 0, stream, qb, kb, vtb, po, ml);
    hipLaunchKernelGGL(merge_kernel, dim3(64, BB), dim3(256), 0, stream, po, ml, out);
}

// Round 20
// 65.827 us; speedup vs baseline: 1.3938x; 1.3938x over previous
//
#include <hip/hip_runtime.h>
#include <hip/hip_bf16.h>

#define BB 4
#define TT 4096
#define DM 1024
#define DK 64
#define NSPLIT 8

using f32x4  = __attribute__((ext_vector_type(4))) float;
using bf16x8 = __attribute__((ext_vector_type(8))) short;

__device__ __forceinline__ short f2bf(float f) {
    __hip_bfloat16 h = __float2bfloat16(f);
    return __builtin_bit_cast(short, h);
}
__device__ __forceinline__ float bf2f(short s) {
    unsigned int u = ((unsigned int)(unsigned short)s) << 16;
    return __builtin_bit_cast(float, u);
}

// ---------------- Kernel 0: pack Wq|Wk|Wv (f32 [1024][64]) -> Wt bf16 [192][1024]
__global__ __launch_bounds__(256) void wt_kernel(const float* __restrict__ Wq,
                                                 const float* __restrict__ Wk,
                                                 const float* __restrict__ Wv,
                                                 short* __restrict__ Wt) {
    int idx = blockIdx.x * 256 + threadIdx.x;
    if (idx >= 192 * 1024) return;
    int n = idx >> 10;
    int m = idx & 1023;
    const float* W = (n < 64) ? Wq : (n < 128) ? Wk : Wv;
    int c = n & 63;
    Wt[idx] = f2bf(W[m * 64 + c]);
}

// ---------------- Kernel 1: FUSED QKV projection (R18 structure) + global_load_lds B
// B panel (192x64 bf16/chunk) DMA'd straight to LDS: linear dest (wave-uniform
// base + lane*16), swizzle carried by the SOURCE column (rule: both-sides-or-
// neither). A reg-staged bf16 as in R18. 12 MFMA/chunk/wave. Grid 512 = 2/CU.
// q is pre-scaled by 1/8 (folded attention scale).
__global__ __launch_bounds__(256, 2) void proj_rope(const float* __restrict__ x,
                                                    const float* __restrict__ freqs,
                                                    const short* __restrict__ Wt,
                                                    short* __restrict__ q,
                                                    short* __restrict__ k,
                                                    short* __restrict__ vt)
{
    __shared__ short As[2][2048];     // [32][64] bf16, unit-XOR-swizzled (4 KB each)
    __shared__ short Bs[2][12288];    // [192][64] bf16, pre-swizzled data (24 KB each)

    int t  = threadIdx.x;
    int w  = t >> 6;
    int l  = t & 63;
    int lr = l & 15;
    int lg = (l >> 4) & 3;
    int wr = w & 1;                   // row group (16 rows)
    int wc = w >> 1;                  // col group (2 n-tiles of 16)
    int bx = blockIdx.x;
    int mt = (bx & 7) * 64 + (bx >> 3);   // 0..511, XCD-striped
    int m0 = mt * 32;

    // A staging geometry (reg->LDS with f2bf at stage, as R18)
    int arow = t >> 3, au = t & 7;
    int aswz = arow & 7;
    const float* gA = x + (size_t)(m0 + arow) * DM + au * 8;

    // B direct-to-LDS: thread t covers row (t>>3)+j*32, stored unit (t&7).
    // Source column unit carries the swizzle: (t&7)^((t>>3)&7).
    const short* gBsw = Wt + (size_t)(t >> 3) * DM + (((t & 7) ^ ((t >> 3) & 7)) << 3);
    int wvsh = (t >> 6) * 512;        // wave-uniform LDS offset (shorts) within a j-slab

    f32x4 ar[2];

#define LOADA(c_) do { int kk = (c_) << 6;                      \
        ar[0] = *(const f32x4*)(gA + kk);                       \
        ar[1] = *(const f32x4*)(gA + kk + 4);                   \
    } while (0)

#define WRITEA(buf_) do {                                                      \
        bf16x8 a0_;                                                            \
        _Pragma("unroll")                                                      \
        for (int j_ = 0; j_ < 4; ++j_) {                                       \
            a0_[j_] = f2bf(ar[0][j_]); a0_[4 + j_] = f2bf(ar[1][j_]);          \
        }                                                                      \
        *(bf16x8*)&As[buf_][arow * 64 + ((au ^ aswz) << 3)] = a0_;             \
    } while (0)

#define ISSUEB(buf_, c_) do { int kk = (c_) << 6;                              \
        _Pragma("unroll")                                                      \
        for (int j_ = 0; j_ < 6; ++j_)                                         \
            __builtin_amdgcn_global_load_lds(                                  \
                (const __attribute__((address_space(1))) void*)(gBsw + (size_t)(j_ * 32) * DM + kk), \
                (__attribute__((address_space(3))) void*)&Bs[buf_][j_ * 2048 + wvsh], \
                16, 0, 0);                                                     \
    } while (0)

    f32x4 acc[6];                     // [nh*2+ntl]
#pragma unroll
    for (int i = 0; i < 6; ++i) acc[i] = (f32x4){0.f, 0.f, 0.f, 0.f};

    int r7 = lr & 7;
    int amrow = (wr * 16 + lr) * 64;
    int cur = 0;

#define COMPUTE() do {                                                         \
        _Pragma("unroll")                                                      \
        for (int s_ = 0; s_ < 2; ++s_) {                                       \
            int u0_ = s_ * 4 + lg;                                             \
            bf16x8 af_ = *(const bf16x8*)&As[cur][amrow + ((u0_ ^ r7) << 3)];  \
            _Pragma("unroll")                                                  \
            for (int nh_ = 0; nh_ < 3; ++nh_)                                  \
                _Pragma("unroll")                                              \
                for (int ntl_ = 0; ntl_ < 2; ++ntl_) {                         \
                    int row_ = nh_ * 64 + (wc * 2 + ntl_) * 16 + lr;           \
                    bf16x8 bfr_ = *(const bf16x8*)&Bs[cur][row_ * 64 + ((u0_ ^ r7) << 3)]; \
                    acc[nh_ * 2 + ntl_] = __builtin_amdgcn_mfma_f32_16x16x32_bf16(af_, bfr_, acc[nh_ * 2 + ntl_], 0, 0, 0); \
                }                                                              \
        }                                                                      \
    } while (0)

    // prologue
    LOADA(0); WRITEA(0); LOADA(1);
    ISSUEB(0, 0);
    __syncthreads();

    for (int ch = 0; ch < 16; ++ch) {
        if (ch + 1 < 16) ISSUEB(cur ^ 1, ch + 1);   // DMA next B while computing
        COMPUTE();
        if (ch + 1 < 16) {
            WRITEA(cur ^ 1);
            if (ch + 2 < 16) LOADA(ch + 2);
            __syncthreads();                        // drains DMA + makes A visible
            cur ^= 1;
        }
    }
#undef LOADA
#undef WRITEA
#undef ISSUEB
#undef COMPUTE

    // ---- q, k epilogue with fused RoPE
#pragma unroll
    for (int nh = 0; nh < 2; ++nh) {
        short* dst = nh ? k : q;
        float postscale = nh ? 1.0f : 0.125f;
#pragma unroll
        for (int r = 0; r < 4; ++r) {
            int tg = m0 + wr * 16 + lg * 4 + r;
            int tt = tg & (TT - 1);
#pragma unroll
            for (int ntl = 0; ntl < 2; ++ntl) {
                int c = wc * 32 + ntl * 16 + lr;
                float e = acc[nh * 2 + ntl][r];
                float p = __shfl_xor(e, 1);
                float2 f = ((const float2*)freqs)[(size_t)tt * 32 + (c >> 1)];
                float sgn = (c & 1) ? f.y : -f.y;
                dst[(size_t)tg * DK + c] = f2bf((e * f.x + p * sgn) * postscale);
            }
        }
    }

    // ---- V epilogue: stage 32x64 bf16 in LDS (reuse As), write vt[b][c][t] coalesced
    __syncthreads();
    short* vs = &As[0][0];
#pragma unroll
    for (int r = 0; r < 4; ++r)
#pragma unroll
        for (int ntl = 0; ntl < 2; ++ntl)
            vs[(wr * 16 + lg * 4 + r) * 64 + wc * 32 + ntl * 16 + lr] = f2bf(acc[4 + ntl][r]);
    __syncthreads();
    int b    = mt >> 7;
    int tt0  = (mt & 127) * 32;
    int c    = t >> 2;
    int tgrp = t & 3;
    bf16x8 v0;
#pragma unroll
    for (int j = 0; j < 8; ++j) v0[j] = vs[(tgrp * 8 + j) * 64 + c];
    *(bf16x8*)(vt + ((size_t)b * DK + c) * TT + tt0 + tgrp * 8) = v0;
}

// ---------------- Kernel 2: causal flash attention (R8 config — best measured, (256,4))
__global__ __launch_bounds__(256, 4) void attn_kernel(const short* __restrict__ q,
                                                      const short* __restrict__ k,
                                                      const short* __restrict__ vt,
                                                      short* __restrict__ po,
                                                      float* __restrict__ ml)
{
    __shared__ short Kb[64][64];
    __shared__ short Vb[64][64];
    __shared__ short pbuf[4][16][72];

    int w  = threadIdx.x >> 6;
    int l  = threadIdx.x & 63;
    int lr = l & 15;
    int lg = l >> 4;
    int b  = blockIdx.y;
    int s  = blockIdx.z;
    int qt = 63 - blockIdx.x;
    int q0 = qt * 64;
    int qrow_wave = q0 + w * 16;

    const short* qB = q  + (size_t)b * TT * DK;
    const short* kB = k  + (size_t)b * TT * DK;
    const short* vB = vt + (size_t)b * DK * TT;

    bf16x8 qf0 = *(const bf16x8*)(qB + (size_t)(qrow_wave + lr) * DK + 8 * lg);
    bf16x8 qf1 = *(const bf16x8*)(qB + (size_t)(qrow_wave + lr) * DK + 32 + 8 * lg);

    f32x4 of[4];
#pragma unroll
    for (int i = 0; i < 4; ++i) of[i] = (f32x4){0.f, 0.f, 0.f, 0.f};
    float m[4], lsum[4];
#pragma unroll
    for (int r = 0; r < 4; ++r) { m[r] = -INFINITY; lsum[r] = 0.f; }

    int nt = (qt >= s) ? ((qt - s + NSPLIT) >> 3) : 0;

    int srow = threadIdx.x >> 2;
    int u0   = (threadIdx.x & 3) * 2;
    int p0s  = ((u0) ^ (srow & 7)) * 8;
    int p1s  = ((u0 + 1) ^ (srow & 7)) * 8;

    bf16x8 kr0, kr1, vr0, vr1;
    short* mypb = &pbuf[w][0][0];

#define ISSUE(tile_) do {                                                        \
        int kv0_ = (tile_) << 6;                                                 \
        const short* gk_ = kB + (size_t)(kv0_ + srow) * DK + (u0 * 8);           \
        const short* gv_ = vB + (size_t)srow * TT + kv0_ + (u0 * 8);             \
        kr0 = *(const bf16x8*)gk_; kr1 = *(const bf16x8*)(gk_ + 8);              \
        vr0 = *(const bf16x8*)gv_; vr1 = *(const bf16x8*)(gv_ + 8);              \
    } while (0)

#define WRITE() do {                                                             \
        *(bf16x8*)&Kb[srow][p0s] = kr0;                                         \
        *(bf16x8*)&Kb[srow][p1s] = kr1;                                         \
        *(bf16x8*)&Vb[srow][p0s] = vr0;                                         \
        *(bf16x8*)&Vb[srow][p1s] = vr1;                                         \
    } while (0)

    if (nt > 0) {
        ISSUE(s); WRITE();
        if (nt > 1) ISSUE(s + NSPLIT);
        __syncthreads();
        for (int i = 0; i < nt; ++i) {
            int kv0 = (s + i * NSPLIT) << 6;

            // ---- QK^T
            f32x4 sc[4];
#pragma unroll
            for (int c = 0; c < 4; ++c) sc[c] = (f32x4){0.f, 0.f, 0.f, 0.f};
#pragma unroll
            for (int c = 0; c < 4; ++c) {
                int row = c * 16 + lr;
                bf16x8 kf0 = *(const bf16x8*)&Kb[row][((lg) ^ (row & 7)) * 8];
                bf16x8 kf1 = *(const bf16x8*)&Kb[row][((4 + lg) ^ (row & 7)) * 8];
                sc[c] = __builtin_amdgcn_mfma_f32_16x16x32_bf16(qf0, kf0, sc[c], 0, 0, 0);
                sc[c] = __builtin_amdgcn_mfma_f32_16x16x32_bf16(qf1, kf1, sc[c], 0, 0, 0);
            }

            // ---- mask only on the diagonal tile
            if (kv0 == q0) {
#pragma unroll
                for (int r = 0; r < 4; ++r) {
                    int qg = qrow_wave + lg * 4 + r;
#pragma unroll
                    for (int c = 0; c < 4; ++c)
                        sc[c][r] = (kv0 + c * 16 + lr <= qg) ? sc[c][r] : -INFINITY;
                }
            }

            // ---- local per-lane row max; gate the expensive path on it
            float mx[4];
#pragma unroll
            for (int r = 0; r < 4; ++r)
                mx[r] = fmaxf(fmaxf(sc[0][r], sc[1][r]), fmaxf(sc[2][r], sc[3][r]));
            bool needA = (mx[0] > m[0] + 8.f) || (mx[1] > m[1] + 8.f) ||
                         (mx[2] > m[2] + 8.f) || (mx[3] > m[3] + 8.f);
            if (__any(needA)) {
#pragma unroll
                for (int r = 0; r < 4; ++r) {
                    float t2 = mx[r];
                    t2 = fmaxf(t2, __shfl_xor(t2, 1));
                    t2 = fmaxf(t2, __shfl_xor(t2, 2));
                    t2 = fmaxf(t2, __shfl_xor(t2, 4));
                    t2 = fmaxf(t2, __shfl_xor(t2, 8));
                    float mn = fmaxf(m[r], t2);
                    float alpha = __expf(m[r] - mn);   // uniform across 16-lane group
                    m[r] = mn;
                    lsum[r] *= alpha;                  // per-lane partial scaled exactly
#pragma unroll
                    for (int dt = 0; dt < 4; ++dt) of[dt][r] *= alpha;
                }
            }
#pragma unroll
            for (int r = 0; r < 4; ++r) {
                float p0 = __expf(sc[0][r] - m[r]);
                float p1 = __expf(sc[1][r] - m[r]);
                float p2 = __expf(sc[2][r] - m[r]);
                float p3 = __expf(sc[3][r] - m[r]);
                lsum[r] += (p0 + p1) + (p2 + p3);      // reduce deferred to epilogue
                int prow = (lg * 4 + r) * 72;
                mypb[prow + lr]      = f2bf(p0);
                mypb[prow + 16 + lr] = f2bf(p1);
                mypb[prow + 32 + lr] = f2bf(p2);
                mypb[prow + 48 + lr] = f2bf(p3);
            }

            // ---- PV
#pragma unroll
            for (int ks = 0; ks < 2; ++ks) {
                bf16x8 pa = *(const bf16x8*)(mypb + lr * 72 + ks * 32 + 8 * lg);
#pragma unroll
                for (int dt = 0; dt < 4; ++dt) {
                    int row = dt * 16 + lr;
                    bf16x8 vf = *(const bf16x8*)&Vb[row][((ks * 4 + lg) ^ (row & 7)) * 8];
                    of[dt] = __builtin_amdgcn_mfma_f32_16x16x32_bf16(pa, vf, of[dt], 0, 0, 0);
                }
            }

            if (i + 1 < nt) {
                __syncthreads();                 // all waves done reading Kb/Vb
                WRITE();                          // next tile regs -> LDS
                if (i + 2 < nt) ISSUE(s + (i + 2) * NSPLIT);
                __syncthreads();                 // writes visible
            }
        }
    }
#undef ISSUE
#undef WRITE

    // epilogue: one cross-lane lsum reduce
#pragma unroll
    for (int r = 0; r < 4; ++r) {
        float ps = lsum[r];
        ps += __shfl_xor(ps, 1);
        ps += __shfl_xor(ps, 2);
        ps += __shfl_xor(ps, 4);
        ps += __shfl_xor(ps, 8);
        lsum[r] = ps;
    }

    short* myo  = po + (((size_t)b * 64 + qt) * NSPLIT + s) * 4096;
    float* myml = ml + (((size_t)b * 64 + qt) * NSPLIT + s) * 128;
#pragma unroll
    for (int r = 0; r < 4; ++r) {
        int row = w * 16 + lg * 4 + r;
#pragma unroll
        for (int dt = 0; dt < 4; ++dt) myo[row * 64 + dt * 16 + lr] = f2bf(of[dt][r]);
        if (lr == 0) { myml[row] = m[r]; myml[64 + row] = lsum[r]; }
    }
}

// ---------------- Kernel 3: merge the 8 kv-split partials (po bf16)
__global__ __launch_bounds__(256) void merge_kernel(const short* __restrict__ po,
                                                    const float* __restrict__ ml,
                                                    float* __restrict__ out)
{
    int qt = blockIdx.x;
    int b  = blockIdx.y;
    int row = threadIdx.x >> 2;
    int cg  = threadIdx.x & 3;

    size_t mlbase = ((size_t)b * 64 + qt) * NSPLIT * 128;
    float mm[NSPLIT], llv[NSPLIT];
#pragma unroll
    for (int s = 0; s < NSPLIT; ++s) {
        mm[s]  = ml[mlbase + s * 128 + row];
        llv[s] = ml[mlbase + s * 128 + 64 + row];
    }
    float M = -INFINITY;
#pragma unroll
    for (int s = 0; s < NSPLIT; ++s) M = fmaxf(M, mm[s]);
    float e[NSPLIT], den = 0.f;
#pragma unroll
    for (int s = 0; s < NSPLIT; ++s) { e[s] = __expf(mm[s] - M); den += e[s] * llv[s]; }
    float inv = 1.0f / den;

    size_t pbase = ((size_t)b * 64 + qt) * NSPLIT * 4096;
#pragma unroll
    for (int jj = 0; jj < 2; ++jj) {
        int col = cg * 16 + jj * 8;
        float acc8[8];
#pragma unroll
        for (int e2 = 0; e2 < 8; ++e2) acc8[e2] = 0.f;
#pragma unroll
        for (int s = 0; s < NSPLIT; ++s) {
            bf16x8 v = *(const bf16x8*)(po + pbase + s * 4096 + row * 64 + col);
#pragma unroll
            for (int e2 = 0; e2 < 8; ++e2) acc8[e2] += e[s] * bf2f(v[e2]);
        }
        float* orow = out + ((size_t)b * TT + qt * 64 + row) * DK + col;
#pragma unroll
        for (int e2 = 0; e2 < 8; ++e2) orow[e2] = acc8[e2] * inv;
    }
}

extern "C" void kernel_launch(void* const* d_in, const int* in_sizes, int n_in,
                              void* d_out, int out_size, void* d_ws, size_t ws_size,
                              hipStream_t stream) {
    const float* x     = (const float*)d_in[0];
    const float* freqs = (const float*)d_in[1];
    const float* Wq    = (const float*)d_in[2];
    const float* Wk    = (const float*)d_in[3];
    const float* Wv    = (const float*)d_in[4];
    float* out = (float*)d_out;

    char* ws = (char*)d_ws;
    short* Wt  = (short*)ws;                          // 384 KB
    short* qb  = (short*)(ws + 393216);               // 2 MB
    short* kb  = (short*)(ws + 2490368);              // 2 MB
    short* vtb = (short*)(ws + 4587520);              // 2 MB
    short* po  = (short*)(ws + 6684672);              // 16 MB partial O (bf16)
    float* ml  = (float*)(ws + 23461888);             // 1 MB partial m/l

    hipLaunchKernelGGL(wt_kernel, dim3(768), dim3(256), 0, stream, Wq, Wk, Wv, Wt);
    hipLaunchKernelGGL(proj_rope, dim3(512), dim3(256), 0, stream, x, freqs, Wt, qb, kb, vtb);
    hipLaunchKernelGGL(attn_kernel, dim3(64, BB, NSPLIT), dim3(256), 0, stream, qb, kb, vtb, po, ml);
    hipLaunchKernelGGL(merge_kernel, dim3(64, BB), dim3(256), 0, stream, po, ml, out);
}

// Round 21
// 60.916 us; speedup vs baseline: 1.5062x; 1.0806x over previous
//
#include <hip/hip_runtime.h>
#include <hip/hip_bf16.h>

#define BB 4
#define TT 4096
#define DM 1024
#define DK 64
#define NSPLIT 8

using f32x4  = __attribute__((ext_vector_type(4))) float;
using bf16x8 = __attribute__((ext_vector_type(8))) short;

__device__ __forceinline__ short f2bf(float f) {
    __hip_bfloat16 h = __float2bfloat16(f);
    return __builtin_bit_cast(short, h);
}
__device__ __forceinline__ float bf2f(short s) {
    unsigned int u = ((unsigned int)(unsigned short)s) << 16;
    return __builtin_bit_cast(float, u);
}

// ---------------- Kernel 0: pack Wq|Wk|Wv (f32 [1024][64]) -> Wt bf16 [192][1024]
__global__ __launch_bounds__(256) void wt_kernel(const float* __restrict__ Wq,
                                                 const float* __restrict__ Wk,
                                                 const float* __restrict__ Wv,
                                                 short* __restrict__ Wt) {
    int idx = blockIdx.x * 256 + threadIdx.x;
    if (idx >= 192 * 1024) return;
    int n = idx >> 10;
    int m = idx & 1023;
    const float* W = (n < 64) ? Wq : (n < 128) ? Wk : Wv;
    int c = n & 63;
    Wt[idx] = f2bf(W[m * 64 + c]);
}

// ---------------- Kernel 1: FUSED QKV projection (R18 — best measured config)
// One block computes q,k,v for a 32-row m-tile: 12 MFMA/wave/chunk so the barrier
// interval covers HBM latency via ILP. Reg-staged A (f32->bf16 at stage) + B, both
// to XOR-swizzled LDS dbuf, ~2-chunk load lookahead. Grid 512 = 2 blocks/CU (56 KB).
// q is pre-scaled by 1/8 (folded attention scale).
__global__ __launch_bounds__(256, 2) void proj_rope(const float* __restrict__ x,
                                                    const float* __restrict__ freqs,
                                                    const short* __restrict__ Wt,
                                                    short* __restrict__ q,
                                                    short* __restrict__ k,
                                                    short* __restrict__ vt)
{
    __shared__ short As[2][2048];     // [32][64] bf16, unit-XOR-swizzled (4 KB each)
    __shared__ short Bs[2][12288];    // [192][64] bf16 (q|k|v rows), swizzled (24 KB each)

    int t  = threadIdx.x;
    int w  = t >> 6;
    int l  = t & 63;
    int lr = l & 15;
    int lg = (l >> 4) & 3;
    int wr = w & 1;                   // row group (16 rows)
    int wc = w >> 1;                  // col group (2 n-tiles of 16)
    int bx = blockIdx.x;
    int mt = (bx & 7) * 64 + (bx >> 3);   // 0..511, XCD-striped
    int m0 = mt * 32;

    // staging geometry
    int arow = t >> 3, au = t & 7;    // A: 32 rows x 8 units (8 cols f32 each)
    int aswz = arow & 7;
    int bswz = (t >> 3) & 7;          // B rows j*32+(t>>3): swz = (t>>3)&7 for all j
    const float* gA = x  + (size_t)(m0 + arow) * DM + au * 8;
    const short* gB = Wt + (size_t)(t >> 3) * DM + (t & 7) * 8;

    f32x4 ar[2]; bf16x8 br[6];

#define LOADG(c_) do { int kk = (c_) << 6;                                      \
        ar[0] = *(const f32x4*)(gA + kk);                                       \
        ar[1] = *(const f32x4*)(gA + kk + 4);                                   \
        _Pragma("unroll")                                                       \
        for (int j_ = 0; j_ < 6; ++j_)                                          \
            br[j_] = *(const bf16x8*)(gB + (size_t)(j_ * 32) * DM + kk);        \
    } while (0)

#define WRITELDS(buf_) do {                                                     \
        bf16x8 a0_;                                                             \
        _Pragma("unroll")                                                       \
        for (int j_ = 0; j_ < 4; ++j_) {                                        \
            a0_[j_] = f2bf(ar[0][j_]); a0_[4 + j_] = f2bf(ar[1][j_]);           \
        }                                                                       \
        *(bf16x8*)&As[buf_][arow * 64 + ((au ^ aswz) << 3)] = a0_;              \
        _Pragma("unroll")                                                       \
        for (int j_ = 0; j_ < 6; ++j_)                                          \
            *(bf16x8*)&Bs[buf_][(j_ * 32 + (t >> 3)) * 64 + (((t & 7) ^ bswz) << 3)] = br[j_]; \
    } while (0)

    f32x4 acc[6];                     // [nh][ntl]
#pragma unroll
    for (int i = 0; i < 6; ++i) acc[i] = (f32x4){0.f, 0.f, 0.f, 0.f};

    LOADG(0); WRITELDS(0); LOADG(1);
    __syncthreads();

    int cur = 0;
    int r7 = lr & 7;
    int amrow = (wr * 16 + lr) * 64;
    for (int ch = 0; ch < 16; ++ch) {
#pragma unroll
        for (int s = 0; s < 2; ++s) {
            int u0 = s * 4 + lg;
            bf16x8 af = *(const bf16x8*)&As[cur][amrow + ((u0 ^ r7) << 3)];
#pragma unroll
            for (int nh = 0; nh < 3; ++nh)
#pragma unroll
                for (int ntl = 0; ntl < 2; ++ntl) {
                    int row = nh * 64 + (wc * 2 + ntl) * 16 + lr;
                    bf16x8 bfr = *(const bf16x8*)&Bs[cur][row * 64 + ((u0 ^ r7) << 3)];
                    acc[nh * 2 + ntl] = __builtin_amdgcn_mfma_f32_16x16x32_bf16(af, bfr, acc[nh * 2 + ntl], 0, 0, 0);
                }
        }
        if (ch + 1 < 16) {
            WRITELDS(cur ^ 1);
            if (ch + 2 < 16) LOADG(ch + 2);
            __syncthreads();
            cur ^= 1;
        }
    }
#undef LOADG
#undef WRITELDS

    // ---- q, k epilogue with fused RoPE
#pragma unroll
    for (int nh = 0; nh < 2; ++nh) {
        short* dst = nh ? k : q;
        float postscale = nh ? 1.0f : 0.125f;
#pragma unroll
        for (int r = 0; r < 4; ++r) {
            int tg = m0 + wr * 16 + lg * 4 + r;
            int tt = tg & (TT - 1);
#pragma unroll
            for (int ntl = 0; ntl < 2; ++ntl) {
                int c = wc * 32 + ntl * 16 + lr;
                float e = acc[nh * 2 + ntl][r];
                float p = __shfl_xor(e, 1);
                float2 f = ((const float2*)freqs)[(size_t)tt * 32 + (c >> 1)];
                float sgn = (c & 1) ? f.y : -f.y;
                dst[(size_t)tg * DK + c] = f2bf((e * f.x + p * sgn) * postscale);
            }
        }
    }

    // ---- V epilogue: stage 32x64 in LDS (reuse As), write vt[b][c][t] coalesced
    __syncthreads();                  // all waves done with As/Bs reads
    short* vs = &As[0][0];
#pragma unroll
    for (int r = 0; r < 4; ++r)
#pragma unroll
        for (int ntl = 0; ntl < 2; ++ntl)
            vs[(wr * 16 + lg * 4 + r) * 64 + wc * 32 + ntl * 16 + lr] = f2bf(acc[4 + ntl][r]);
    __syncthreads();
    int b    = mt >> 7;               // 128 tiles of 32 rows per batch
    int tt0  = (mt & 127) * 32;
    int c    = t >> 2;                // 0..63
    int tgrp = t & 3;                 // 4 groups of 8 rows
    bf16x8 v0;
#pragma unroll
    for (int j = 0; j < 8; ++j) v0[j] = vs[(tgrp * 8 + j) * 64 + c];
    *(bf16x8*)(vt + ((size_t)b * DK + c) * TT + tt0 + tgrp * 8) = v0;
}

// ---------------- Kernel 2: causal flash attention (R8 config — best measured, (256,4))
__global__ __launch_bounds__(256, 4) void attn_kernel(const short* __restrict__ q,
                                                      const short* __restrict__ k,
                                                      const short* __restrict__ vt,
                                                      short* __restrict__ po,
                                                      float* __restrict__ ml)
{
    __shared__ short Kb[64][64];
    __shared__ short Vb[64][64];
    __shared__ short pbuf[4][16][72];

    int w  = threadIdx.x >> 6;
    int l  = threadIdx.x & 63;
    int lr = l & 15;
    int lg = l >> 4;
    int b  = blockIdx.y;
    int s  = blockIdx.z;
    int qt = 63 - blockIdx.x;
    int q0 = qt * 64;
    int qrow_wave = q0 + w * 16;

    const short* qB = q  + (size_t)b * TT * DK;
    const short* kB = k  + (size_t)b * TT * DK;
    const short* vB = vt + (size_t)b * DK * TT;

    bf16x8 qf0 = *(const bf16x8*)(qB + (size_t)(qrow_wave + lr) * DK + 8 * lg);
    bf16x8 qf1 = *(const bf16x8*)(qB + (size_t)(qrow_wave + lr) * DK + 32 + 8 * lg);

    f32x4 of[4];
#pragma unroll
    for (int i = 0; i < 4; ++i) of[i] = (f32x4){0.f, 0.f, 0.f, 0.f};
    float m[4], lsum[4];
#pragma unroll
    for (int r = 0; r < 4; ++r) { m[r] = -INFINITY; lsum[r] = 0.f; }

    int nt = (qt >= s) ? ((qt - s + NSPLIT) >> 3) : 0;

    int srow = threadIdx.x >> 2;
    int u0   = (threadIdx.x & 3) * 2;
    int p0s  = ((u0) ^ (srow & 7)) * 8;
    int p1s  = ((u0 + 1) ^ (srow & 7)) * 8;

    bf16x8 kr0, kr1, vr0, vr1;
    short* mypb = &pbuf[w][0][0];

#define ISSUE(tile_) do {                                                        \
        int kv0_ = (tile_) << 6;                                                 \
        const short* gk_ = kB + (size_t)(kv0_ + srow) * DK + (u0 * 8);           \
        const short* gv_ = vB + (size_t)srow * TT + kv0_ + (u0 * 8);             \
        kr0 = *(const bf16x8*)gk_; kr1 = *(const bf16x8*)(gk_ + 8);              \
        vr0 = *(const bf16x8*)gv_; vr1 = *(const bf16x8*)(gv_ + 8);              \
    } while (0)

#define WRITE() do {                                                             \
        *(bf16x8*)&Kb[srow][p0s] = kr0;                                         \
        *(bf16x8*)&Kb[srow][p1s] = kr1;                                         \
        *(bf16x8*)&Vb[srow][p0s] = vr0;                                         \
        *(bf16x8*)&Vb[srow][p1s] = vr1;                                         \
    } while (0)

    if (nt > 0) {
        ISSUE(s); WRITE();
        if (nt > 1) ISSUE(s + NSPLIT);
        __syncthreads();
        for (int i = 0; i < nt; ++i) {
            int kv0 = (s + i * NSPLIT) << 6;

            // ---- QK^T
            f32x4 sc[4];
#pragma unroll
            for (int c = 0; c < 4; ++c) sc[c] = (f32x4){0.f, 0.f, 0.f, 0.f};
#pragma unroll
            for (int c = 0; c < 4; ++c) {
                int row = c * 16 + lr;
                bf16x8 kf0 = *(const bf16x8*)&Kb[row][((lg) ^ (row & 7)) * 8];
                bf16x8 kf1 = *(const bf16x8*)&Kb[row][((4 + lg) ^ (row & 7)) * 8];
                sc[c] = __builtin_amdgcn_mfma_f32_16x16x32_bf16(qf0, kf0, sc[c], 0, 0, 0);
                sc[c] = __builtin_amdgcn_mfma_f32_16x16x32_bf16(qf1, kf1, sc[c], 0, 0, 0);
            }

            // ---- mask only on the diagonal tile
            if (kv0 == q0) {
#pragma unroll
                for (int r = 0; r < 4; ++r) {
                    int qg = qrow_wave + lg * 4 + r;
#pragma unroll
                    for (int c = 0; c < 4; ++c)
                        sc[c][r] = (kv0 + c * 16 + lr <= qg) ? sc[c][r] : -INFINITY;
                }
            }

            // ---- local per-lane row max; gate the expensive path on it
            float mx[4];
#pragma unroll
            for (int r = 0; r < 4; ++r)
                mx[r] = fmaxf(fmaxf(sc[0][r], sc[1][r]), fmaxf(sc[2][r], sc[3][r]));
            bool needA = (mx[0] > m[0] + 8.f) || (mx[1] > m[1] + 8.f) ||
                         (mx[2] > m[2] + 8.f) || (mx[3] > m[3] + 8.f);
            if (__any(needA)) {
#pragma unroll
                for (int r = 0; r < 4; ++r) {
                    float t2 = mx[r];
                    t2 = fmaxf(t2, __shfl_xor(t2, 1));
                    t2 = fmaxf(t2, __shfl_xor(t2, 2));
                    t2 = fmaxf(t2, __shfl_xor(t2, 4));
                    t2 = fmaxf(t2, __shfl_xor(t2, 8));
                    float mn = fmaxf(m[r], t2);
                    float alpha = __expf(m[r] - mn);   // uniform across 16-lane group
                    m[r] = mn;
                    lsum[r] *= alpha;                  // per-lane partial scaled exactly
#pragma unroll
                    for (int dt = 0; dt < 4; ++dt) of[dt][r] *= alpha;
                }
            }
#pragma unroll
            for (int r = 0; r < 4; ++r) {
                float p0 = __expf(sc[0][r] - m[r]);
                float p1 = __expf(sc[1][r] - m[r]);
                float p2 = __expf(sc[2][r] - m[r]);
                float p3 = __expf(sc[3][r] - m[r]);
                lsum[r] += (p0 + p1) + (p2 + p3);      // reduce deferred to epilogue
                int prow = (lg * 4 + r) * 72;
                mypb[prow + lr]      = f2bf(p0);
                mypb[prow + 16 + lr] = f2bf(p1);
                mypb[prow + 32 + lr] = f2bf(p2);
                mypb[prow + 48 + lr] = f2bf(p3);
            }

            // ---- PV
#pragma unroll
            for (int ks = 0; ks < 2; ++ks) {
                bf16x8 pa = *(const bf16x8*)(mypb + lr * 72 + ks * 32 + 8 * lg);
#pragma unroll
                for (int dt = 0; dt < 4; ++dt) {
                    int row = dt * 16 + lr;
                    bf16x8 vf = *(const bf16x8*)&Vb[row][((ks * 4 + lg) ^ (row & 7)) * 8];
                    of[dt] = __builtin_amdgcn_mfma_f32_16x16x32_bf16(pa, vf, of[dt], 0, 0, 0);
                }
            }

            if (i + 1 < nt) {
                __syncthreads();                 // all waves done reading Kb/Vb
                WRITE();                          // next tile regs -> LDS
                if (i + 2 < nt) ISSUE(s + (i + 2) * NSPLIT);
                __syncthreads();                 // writes visible
            }
        }
    }
#undef ISSUE
#undef WRITE

    // epilogue: one cross-lane lsum reduce
#pragma unroll
    for (int r = 0; r < 4; ++r) {
        float ps = lsum[r];
        ps += __shfl_xor(ps, 1);
        ps += __shfl_xor(ps, 2);
        ps += __shfl_xor(ps, 4);
        ps += __shfl_xor(ps, 8);
        lsum[r] = ps;
    }

    short* myo  = po + (((size_t)b * 64 + qt) * NSPLIT + s) * 4096;
    float* myml = ml + (((size_t)b * 64 + qt) * NSPLIT + s) * 128;
#pragma unroll
    for (int r = 0; r < 4; ++r) {
        int row = w * 16 + lg * 4 + r;
#pragma unroll
        for (int dt = 0; dt < 4; ++dt) myo[row * 64 + dt * 16 + lr] = f2bf(of[dt][r]);
        if (lr == 0) { myml[row] = m[r]; myml[64 + row] = lsum[r]; }
    }
}

// ---------------- Kernel 3: merge the 8 kv-split partials (po bf16)
__global__ __launch_bounds__(256) void merge_kernel(const short* __restrict__ po,
                                                    const float* __restrict__ ml,
                                                    float* __restrict__ out)
{
    int qt = blockIdx.x;
    int b  = blockIdx.y;
    int row = threadIdx.x >> 2;
    int cg  = threadIdx.x & 3;

    size_t mlbase = ((size_t)b * 64 + qt) * NSPLIT * 128;
    float mm[NSPLIT], llv[NSPLIT];
#pragma unroll
    for (int s = 0; s < NSPLIT; ++s) {
        mm[s]  = ml[mlbase + s * 128 + row];
        llv[s] = ml[mlbase + s * 128 + 64 + row];
    }
    float M = -INFINITY;
#pragma unroll
    for (int s = 0; s < NSPLIT; ++s) M = fmaxf(M, mm[s]);
    float e[NSPLIT], den = 0.f;
#pragma unroll
    for (int s = 0; s < NSPLIT; ++s) { e[s] = __expf(mm[s] - M); den += e[s] * llv[s]; }
    float inv = 1.0f / den;

    size_t pbase = ((size_t)b * 64 + qt) * NSPLIT * 4096;
#pragma unroll
    for (int jj = 0; jj < 2; ++jj) {
        int col = cg * 16 + jj * 8;
        float acc8[8];
#pragma unroll
        for (int e2 = 0; e2 < 8; ++e2) acc8[e2] = 0.f;
#pragma unroll
        for (int s = 0; s < NSPLIT; ++s) {
            bf16x8 v = *(const bf16x8*)(po + pbase + s * 4096 + row * 64 + col);
#pragma unroll
            for (int e2 = 0; e2 < 8; ++e2) acc8[e2] += e[s] * bf2f(v[e2]);
        }
        float* orow = out + ((size_t)b * TT + qt * 64 + row) * DK + col;
#pragma unroll
        for (int e2 = 0; e2 < 8; ++e2) orow[e2] = acc8[e2] * inv;
    }
}

extern "C" void kernel_launch(void* const* d_in, const int* in_sizes, int n_in,
                              void* d_out, int out_size, void* d_ws, size_t ws_size,
                              hipStream_t stream) {
    const float* x     = (const float*)d_in[0];
    const float* freqs = (const float*)d_in[1];
    const float* Wq    = (const float*)d_in[2];
    const float* Wk    = (const float*)d_in[3];
    const float* Wv    = (const float*)d_in[4];
    float* out = (float*)d_out;

    char* ws = (char*)d_ws;
    short* Wt  = (short*)ws;                          // 384 KB
    short* qb  = (short*)(ws + 393216);               // 2 MB
    short* kb  = (short*)(ws + 2490368);              // 2 MB
    short* vtb = (short*)(ws + 4587520);              // 2 MB
    short* po  = (short*)(ws + 6684672);              // 16 MB partial O (bf16)
    float* ml  = (float*)(ws + 23461888);             // 1 MB partial m/l

    hipLaunchKernelGGL(wt_kernel, dim3(768), dim3(256), 0, stream, Wq, Wk, Wv, Wt);
    hipLaunchKernelGGL(proj_rope, dim3(512), dim3(256), 0, stream, x, freqs, Wt, qb, kb, vtb);
    hipLaunchKernelGGL(attn_kernel, dim3(64, BB, NSPLIT), dim3(256), 0, stream, qb, kb, vtb, po, ml);
    hipLaunchKernelGGL(merge_kernel, dim3(64, BB), dim3(256), 0, stream, po, ml, out);
}